// Round 1
// baseline (433.974 us; speedup 1.0000x reference)
//
#include <hip/hip_runtime.h>
#include <math.h>

#define BINS   256
#define CH     3
#define NHIST  (CH * BINS)           // 768
#define HW_LOG2_V4 18                // element idx = 4*v4 idx; channel = (v4 >> 18) % 3

// d_ws layout (as unsigned int):
//   ws[0] = min(input) bits   ws[1] = max(input) bits
//   ws[2] = min(target) bits  ws[3] = max(target) bits
//   ws[4          .. 4+768)   = hist(input)  counts
//   ws[4+768      .. 4+1536)  = hist(target) counts

__global__ void init_ws_kernel(unsigned int* ws) {
    int i = blockIdx.x * blockDim.x + threadIdx.x;
    int n = 4 + 2 * NHIST;
    for (int j = i; j < n; j += gridDim.x * blockDim.x) {
        unsigned int v = 0u;
        if (j == 0 || j == 2) v = 0x7F800000u;  // +inf bits (values are >= 0)
        ws[j] = v;
    }
}

__global__ __launch_bounds__(256) void minmax_kernel(const float4* __restrict__ a,
                                                     const float4* __restrict__ b,
                                                     int n4, unsigned int* ws) {
    float mna = INFINITY, mxa = 0.0f, mnb = INFINITY, mxb = 0.0f;
    int stride = gridDim.x * blockDim.x;
    for (int i = blockIdx.x * blockDim.x + threadIdx.x; i < n4; i += stride) {
        float4 va = a[i];
        float4 vb = b[i];
        mna = fminf(mna, fminf(fminf(va.x, va.y), fminf(va.z, va.w)));
        mxa = fmaxf(mxa, fmaxf(fmaxf(va.x, va.y), fmaxf(va.z, va.w)));
        mnb = fminf(mnb, fminf(fminf(vb.x, vb.y), fminf(vb.z, vb.w)));
        mxb = fmaxf(mxb, fmaxf(fmaxf(vb.x, vb.y), fmaxf(vb.z, vb.w)));
    }
    // wave64 shuffle reduce
    for (int off = 32; off > 0; off >>= 1) {
        mna = fminf(mna, __shfl_down(mna, off));
        mxa = fmaxf(mxa, __shfl_down(mxa, off));
        mnb = fminf(mnb, __shfl_down(mnb, off));
        mxb = fmaxf(mxb, __shfl_down(mxb, off));
    }
    if ((threadIdx.x & 63) == 0) {
        // all values >= 0, so float bits compare like unsigned ints
        atomicMin(&ws[0], __float_as_uint(mna));
        atomicMax(&ws[1], __float_as_uint(mxa));
        atomicMin(&ws[2], __float_as_uint(mnb));
        atomicMax(&ws[3], __float_as_uint(mxb));
    }
}

__device__ __forceinline__ int bin_of(float x, float mn, float rg) {
    float d = (x - mn) / rg;          // IEEE div: matches jnp/np float32 normalize
    int bi = (int)floorf(d * 256.0f); // floor(img * bins)
    bi = bi < 0 ? 0 : bi;
    bi = bi > (BINS - 1) ? (BINS - 1) : bi;
    return bi;
}

__global__ __launch_bounds__(256) void hist_kernel(const float4* __restrict__ a,
                                                   const float4* __restrict__ b,
                                                   int n4, unsigned int* ws) {
    __shared__ unsigned int ha[4][NHIST];  // per-wave private copies
    __shared__ unsigned int hb[4][NHIST];
    int tid = threadIdx.x;
    int wv  = tid >> 6;
    for (int j = tid; j < 4 * NHIST; j += blockDim.x) {
        (&ha[0][0])[j] = 0u;
        (&hb[0][0])[j] = 0u;
    }
    __syncthreads();

    float mn_a = __uint_as_float(ws[0]);
    float rg_a = __uint_as_float(ws[1]) - mn_a;
    float mn_b = __uint_as_float(ws[2]);
    float rg_b = __uint_as_float(ws[3]) - mn_b;

    int stride = gridDim.x * blockDim.x;
    for (int i = blockIdx.x * blockDim.x + tid; i < n4; i += stride) {
        float4 va = a[i];
        float4 vb = b[i];
        int c = (i >> HW_LOG2_V4) % 3;   // all 4 elements share one channel
        unsigned int* HA = &ha[wv][c * BINS];
        unsigned int* HB = &hb[wv][c * BINS];
        atomicAdd(&HA[bin_of(va.x, mn_a, rg_a)], 1u);
        atomicAdd(&HA[bin_of(va.y, mn_a, rg_a)], 1u);
        atomicAdd(&HA[bin_of(va.z, mn_a, rg_a)], 1u);
        atomicAdd(&HA[bin_of(va.w, mn_a, rg_a)], 1u);
        atomicAdd(&HB[bin_of(vb.x, mn_b, rg_b)], 1u);
        atomicAdd(&HB[bin_of(vb.y, mn_b, rg_b)], 1u);
        atomicAdd(&HB[bin_of(vb.z, mn_b, rg_b)], 1u);
        atomicAdd(&HB[bin_of(vb.w, mn_b, rg_b)], 1u);
    }
    __syncthreads();

    for (int j = tid; j < NHIST; j += blockDim.x) {
        unsigned int sa = ha[0][j] + ha[1][j] + ha[2][j] + ha[3][j];
        unsigned int sb = hb[0][j] + hb[1][j] + hb[2][j] + hb[3][j];
        if (sa) atomicAdd(&ws[4 + j], sa);
        if (sb) atomicAdd(&ws[4 + NHIST + j], sb);
    }
}

__global__ __launch_bounds__(256) void finalize_kernel(const unsigned int* __restrict__ ws,
                                                       float* __restrict__ out) {
    __shared__ float sred[4];
    int tid = threadIdx.x;
    float s = 0.0f;
    for (int j = tid; j < NHIST; j += blockDim.x) {
        float d = (float)ws[4 + j] - (float)ws[4 + NHIST + j];
        s += d * d;
    }
    for (int off = 32; off > 0; off >>= 1) s += __shfl_down(s, off);
    if ((tid & 63) == 0) sred[tid >> 6] = s;
    __syncthreads();
    if (tid == 0) {
        float total = sred[0] + sred[1] + sred[2] + sred[3];
        float loss = total / (float)NHIST;          // jnp.mean over C*bins
        float r = 1.0f - 1.0f / loss;               // normalize_loss_output
        if (isinf(r)) r = 1.0f;                     // inf -> 1.0 (covers -inf too per ref order)
        out[0] = r;
    }
}

extern "C" void kernel_launch(void* const* d_in, const int* in_sizes, int n_in,
                              void* d_out, int out_size, void* d_ws, size_t ws_size,
                              hipStream_t stream) {
    const float4* a = (const float4*)d_in[0];
    const float4* b = (const float4*)d_in[1];
    unsigned int* ws = (unsigned int*)d_ws;
    float* out = (float*)d_out;
    int n  = in_sizes[0];        // 16*3*1024*1024 = 50331648
    int n4 = n >> 2;             // 12582912 float4s

    init_ws_kernel<<<8, 256, 0, stream>>>(ws);
    minmax_kernel<<<1536, 256, 0, stream>>>(a, b, n4, ws);
    hist_kernel<<<1536, 256, 0, stream>>>(a, b, n4, ws);
    finalize_kernel<<<1, 256, 0, stream>>>(ws, out);
}

// Round 2
// 151.939 us; speedup vs baseline: 2.8562x; 2.8562x over previous
//
#include <hip/hip_runtime.h>
#include <math.h>

#define BINS   256
#define CH     3
#define NHIST  (CH * BINS)           // 768
#define HW_LOG2_V4 18                // channel of float4 i = (i >> 18) % 3  (H*W = 1<<20)
#define NCOPY  8                     // hist accumulator copies (cuts same-address atomic contention)
#define NBLK   1536

// d_ws layout (unsigned int):
//   [0..3]                         : final min_a, max_a, min_b, max_b (float bits)
//   [4 .. 4 + NCOPY*2*NHIST)       : hist copies: copy c -> [a: NHIST][b: NHIST]
//   [WS_PART .. WS_PART+4*NBLK)    : per-block minmax partials {mna,mxa,mnb,mxb}
#define WS_HIST 4
#define WS_PART (4 + NCOPY * 2 * NHIST)   // 12292

__global__ void init_ws_kernel(unsigned int* ws) {
    int i = blockIdx.x * blockDim.x + threadIdx.x;
    for (int j = WS_HIST + i; j < WS_PART; j += gridDim.x * blockDim.x)
        ws[j] = 0u;
}

__device__ __forceinline__ float min4(float4 v) { return fminf(fminf(v.x, v.y), fminf(v.z, v.w)); }
__device__ __forceinline__ float max4(float4 v) { return fmaxf(fmaxf(v.x, v.y), fmaxf(v.z, v.w)); }

// Pass 1: per-block min/max partials. NO global atomics (same-address atomic
// serialization was 300+ us in R0). 4x unrolled for memory-level parallelism.
__global__ __launch_bounds__(256) void minmax_part_kernel(const float4* __restrict__ a,
                                                          const float4* __restrict__ b,
                                                          int n4, unsigned int* __restrict__ part) {
    float mna = INFINITY, mxa = -INFINITY, mnb = INFINITY, mxb = -INFINITY;
    int tid = threadIdx.x;
    int stride = gridDim.x * blockDim.x;
    int i = blockIdx.x * blockDim.x + tid;
    int bound = n4 - 3 * stride;
    for (; i < bound; i += 4 * stride) {
        float4 a0 = a[i], a1 = a[i + stride], a2 = a[i + 2 * stride], a3 = a[i + 3 * stride];
        float4 b0 = b[i], b1 = b[i + stride], b2 = b[i + 2 * stride], b3 = b[i + 3 * stride];
        mna = fminf(mna, fminf(fminf(min4(a0), min4(a1)), fminf(min4(a2), min4(a3))));
        mxa = fmaxf(mxa, fmaxf(fmaxf(max4(a0), max4(a1)), fmaxf(max4(a2), max4(a3))));
        mnb = fminf(mnb, fminf(fminf(min4(b0), min4(b1)), fminf(min4(b2), min4(b3))));
        mxb = fmaxf(mxb, fmaxf(fmaxf(max4(b0), max4(b1)), fmaxf(max4(b2), max4(b3))));
    }
    for (; i < n4; i += stride) {
        float4 va = a[i], vb = b[i];
        mna = fminf(mna, min4(va));  mxa = fmaxf(mxa, max4(va));
        mnb = fminf(mnb, min4(vb));  mxb = fmaxf(mxb, max4(vb));
    }
    // wave64 shuffle reduce
    for (int off = 32; off > 0; off >>= 1) {
        mna = fminf(mna, __shfl_down(mna, off));
        mxa = fmaxf(mxa, __shfl_down(mxa, off));
        mnb = fminf(mnb, __shfl_down(mnb, off));
        mxb = fmaxf(mxb, __shfl_down(mxb, off));
    }
    __shared__ float red[4][4];
    int wv = tid >> 6;
    if ((tid & 63) == 0) {
        red[wv][0] = mna; red[wv][1] = mxa; red[wv][2] = mnb; red[wv][3] = mxb;
    }
    __syncthreads();
    if (tid == 0) {
        unsigned int* p = &part[blockIdx.x * 4];
        p[0] = __float_as_uint(fminf(fminf(red[0][0], red[1][0]), fminf(red[2][0], red[3][0])));
        p[1] = __float_as_uint(fmaxf(fmaxf(red[0][1], red[1][1]), fmaxf(red[2][1], red[3][1])));
        p[2] = __float_as_uint(fminf(fminf(red[0][2], red[1][2]), fminf(red[2][2], red[3][2])));
        p[3] = __float_as_uint(fmaxf(fmaxf(red[0][3], red[1][3]), fmaxf(red[2][3], red[3][3])));
    }
}

// Pass 1b: one block reduces the 1536 partials -> ws[0..3].
__global__ __launch_bounds__(256) void minmax_reduce_kernel(const unsigned int* __restrict__ part,
                                                            int nblk, unsigned int* __restrict__ ws) {
    int tid = threadIdx.x;
    float mna = INFINITY, mxa = -INFINITY, mnb = INFINITY, mxb = -INFINITY;
    for (int j = tid; j < nblk; j += blockDim.x) {
        mna = fminf(mna, __uint_as_float(part[4 * j + 0]));
        mxa = fmaxf(mxa, __uint_as_float(part[4 * j + 1]));
        mnb = fminf(mnb, __uint_as_float(part[4 * j + 2]));
        mxb = fmaxf(mxb, __uint_as_float(part[4 * j + 3]));
    }
    for (int off = 32; off > 0; off >>= 1) {
        mna = fminf(mna, __shfl_down(mna, off));
        mxa = fmaxf(mxa, __shfl_down(mxa, off));
        mnb = fminf(mnb, __shfl_down(mnb, off));
        mxb = fmaxf(mxb, __shfl_down(mxb, off));
    }
    __shared__ float red[4][4];
    int wv = tid >> 6;
    if ((tid & 63) == 0) {
        red[wv][0] = mna; red[wv][1] = mxa; red[wv][2] = mnb; red[wv][3] = mxb;
    }
    __syncthreads();
    if (tid == 0) {
        ws[0] = __float_as_uint(fminf(fminf(red[0][0], red[1][0]), fminf(red[2][0], red[3][0])));
        ws[1] = __float_as_uint(fmaxf(fmaxf(red[0][1], red[1][1]), fmaxf(red[2][1], red[3][1])));
        ws[2] = __float_as_uint(fminf(fminf(red[0][2], red[1][2]), fminf(red[2][2], red[3][2])));
        ws[3] = __float_as_uint(fmaxf(fmaxf(red[0][3], red[1][3]), fmaxf(red[2][3], red[3][3])));
    }
}

__device__ __forceinline__ int bin_of(float x, float mn, float rg) {
    float d = (x - mn) / rg;          // IEEE div: matches jnp/np float32 normalize
    int bi = (int)floorf(d * 256.0f); // floor(img * bins)
    bi = bi < 0 ? 0 : bi;
    bi = bi > (BINS - 1) ? (BINS - 1) : bi;
    return bi;
}

__global__ __launch_bounds__(256) void hist_kernel(const float4* __restrict__ a,
                                                   const float4* __restrict__ b,
                                                   int n4, unsigned int* ws) {
    __shared__ unsigned int ha[4][NHIST];  // per-wave private copies
    __shared__ unsigned int hb[4][NHIST];
    int tid = threadIdx.x;
    int wv  = tid >> 6;
    for (int j = tid; j < 4 * NHIST; j += blockDim.x) {
        (&ha[0][0])[j] = 0u;
        (&hb[0][0])[j] = 0u;
    }
    __syncthreads();

    float mn_a = __uint_as_float(ws[0]);
    float rg_a = __uint_as_float(ws[1]) - mn_a;
    float mn_b = __uint_as_float(ws[2]);
    float rg_b = __uint_as_float(ws[3]) - mn_b;

    int stride = gridDim.x * blockDim.x;
    for (int i = blockIdx.x * blockDim.x + tid; i < n4; i += stride) {
        float4 va = a[i];
        float4 vb = b[i];
        int c = (i >> HW_LOG2_V4) % 3;   // all 4 elements share one channel
        unsigned int* HA = &ha[wv][c * BINS];
        unsigned int* HB = &hb[wv][c * BINS];
        atomicAdd(&HA[bin_of(va.x, mn_a, rg_a)], 1u);
        atomicAdd(&HA[bin_of(va.y, mn_a, rg_a)], 1u);
        atomicAdd(&HA[bin_of(va.z, mn_a, rg_a)], 1u);
        atomicAdd(&HA[bin_of(va.w, mn_a, rg_a)], 1u);
        atomicAdd(&HB[bin_of(vb.x, mn_b, rg_b)], 1u);
        atomicAdd(&HB[bin_of(vb.y, mn_b, rg_b)], 1u);
        atomicAdd(&HB[bin_of(vb.z, mn_b, rg_b)], 1u);
        atomicAdd(&HB[bin_of(vb.w, mn_b, rg_b)], 1u);
    }
    __syncthreads();

    // 8-way copy split: per-address atomic count drops 1536 -> 192
    unsigned int* dst = &ws[WS_HIST + (blockIdx.x & (NCOPY - 1)) * 2 * NHIST];
    for (int j = tid; j < NHIST; j += blockDim.x) {
        unsigned int sa = ha[0][j] + ha[1][j] + ha[2][j] + ha[3][j];
        unsigned int sb = hb[0][j] + hb[1][j] + hb[2][j] + hb[3][j];
        if (sa) atomicAdd(&dst[j], sa);
        if (sb) atomicAdd(&dst[NHIST + j], sb);
    }
}

__global__ __launch_bounds__(256) void finalize_kernel(const unsigned int* __restrict__ ws,
                                                       float* __restrict__ out) {
    __shared__ float sred[4];
    int tid = threadIdx.x;
    float s = 0.0f;
    for (int j = tid; j < NHIST; j += blockDim.x) {
        unsigned int sa = 0u, sb = 0u;
        for (int c = 0; c < NCOPY; ++c) {
            sa += ws[WS_HIST + c * 2 * NHIST + j];
            sb += ws[WS_HIST + c * 2 * NHIST + NHIST + j];
        }
        float d = (float)sa - (float)sb;
        s += d * d;
    }
    for (int off = 32; off > 0; off >>= 1) s += __shfl_down(s, off);
    if ((tid & 63) == 0) sred[tid >> 6] = s;
    __syncthreads();
    if (tid == 0) {
        float total = sred[0] + sred[1] + sred[2] + sred[3];
        float loss = total / (float)NHIST;          // jnp.mean over C*bins
        float r = 1.0f - 1.0f / loss;               // normalize_loss_output
        if (isinf(r)) r = 1.0f;
        out[0] = r;
    }
}

extern "C" void kernel_launch(void* const* d_in, const int* in_sizes, int n_in,
                              void* d_out, int out_size, void* d_ws, size_t ws_size,
                              hipStream_t stream) {
    const float4* a = (const float4*)d_in[0];
    const float4* b = (const float4*)d_in[1];
    unsigned int* ws = (unsigned int*)d_ws;
    float* out = (float*)d_out;
    int n  = in_sizes[0];        // 16*3*1024*1024 = 50331648
    int n4 = n >> 2;             // 12582912 float4s

    init_ws_kernel<<<16, 256, 0, stream>>>(ws);
    minmax_part_kernel<<<NBLK, 256, 0, stream>>>(a, b, n4, &ws[WS_PART]);
    minmax_reduce_kernel<<<1, 256, 0, stream>>>(&ws[WS_PART], NBLK, ws);
    hist_kernel<<<NBLK, 256, 0, stream>>>(a, b, n4, ws);
    finalize_kernel<<<1, 256, 0, stream>>>(ws, out);
}